// Round 8
// baseline (341.662 us; speedup 1.0000x reference)
//
#include <hip/hip_runtime.h>
#include <hip/hip_bf16.h>

typedef unsigned int uint;
typedef unsigned short ushort_t;
typedef unsigned long long u64;
typedef __attribute__((ext_vector_type(8))) short short8;
typedef __attribute__((ext_vector_type(4))) float floatx4;

#define NB 8
#define NP 4096
#define ND 128
#define NK 16
#define NC 64
#define NPTS 32768   // NB*NP
#define QB 8         // queries per k_knn block (r7-proven)
#define CAP5 256     // per-query candidate j-buffer (cheap filter adds ~15-20% to
                     // the proven ~110 max -> ~130, 2x margin)
#define NQE 8        // sequential queries per k_edge wave

__device__ __forceinline__ float bf2f(ushort_t h){ return __uint_as_float(((uint)h)<<16); }
__device__ __forceinline__ ushort_t f2bf(float f){
  uint u = __float_as_uint(f);
  u = u + 0x7FFFu + ((u>>16)&1u);
  return (ushort_t)(u>>16);
}
// dtype-polymorphic input load (f32=1: fp32 array, f32=0: bf16 array)
__device__ __forceinline__ float ldin(const void* p, long i, int f32){
  return f32 ? ((const float*)p)[i] : bf2f(((const ushort_t*)p)[i]);
}
// dtype-polymorphic output store
__device__ __forceinline__ void stout(void* o, long i, float v, int f32){
  if (f32) ((float*)o)[i] = v; else ((ushort_t*)o)[i] = f2bf(v);
}

// XOR-swizzled LDS element index for 16-row x 64-elem bf16 tiles (128 B rows).
// Keeps 16B alignment for e%8==0; measured conflict-free (BANK_CONFLICT=0, r3-r7).
#define SWZE(row, e) (((row)<<6) + ((e) ^ (((row)&7)<<3)))
// Intra-wave LDS write->read fence (wave-private buffers; DS ops of one wave
// execute in order; asm memory clobber pins compiler ordering). r4-r7-proven.
#define WAVE_SYNC() asm volatile("s_waitcnt lgkmcnt(0)" ::: "memory")

// ---------------- kernel D: detect input dtype ----------------
__global__ __launch_bounds__(256) void k_detect(const uint* __restrict__ w, int* __restrict__ flag){
  __shared__ int cnt;
  if (threadIdx.x == 0) cnt = 0;
  __syncthreads();
  int c = 0;
  for (int i = threadIdx.x; i < 512; i += 256){
    uint u = w[i];
    uint e = (u >> 7) & 0xFFu;
    c += (e >= 100u && e < 128u) ? 1 : 0;
  }
  atomicAdd(&cnt, c);
  __syncthreads();
  if (threadIdx.x == 0) *flag = (cnt < 256) ? 1 : 0;   // 1 => fp32 inputs/outputs
}

// ---------------- kernel 0: pos -> float4 {x,y,z,sq} ----------------
__global__ __launch_bounds__(256) void k_posf(const void* __restrict__ pos, float4* __restrict__ posf,
                                              const int* __restrict__ flag){
#pragma clang fp contract(off)
  int f32 = *flag;
  int p = blockIdx.x*256 + threadIdx.x;
  if (p >= NPTS) return;
  float x = ldin(pos, (long)p*3+0, f32);
  float y = ldin(pos, (long)p*3+1, f32);
  float z = ldin(pos, (long)p*3+2, f32);
  float px = x*x; float py = y*y; float pz = z*z;
  float sq = (px + py) + pz;   // match np.sum(pos*pos,-1) sequential order
  posf[p] = make_float4(x, y, z, sq);
}

// ---------------- kernel 1: exact 17-NN, QB queries per block ----------------
// v9 = r7 threshold logic VERBATIM (granule <<19, +2, atomicMin — proven) +
// cheap-collect stage B:
//   collect if g < Tc[q],  Tc[q] = (Tf + S) - Qw,  S = (Qw+16)*2^-14,
//   g = fma(Qx,px2, fma(Qy,py2, fma(Qz,pz2, pw)))  (4 ops/pair vs 11).
// Superset proof: r6/r7 exact set = {v_exact < Tf}. |g+Qw - v_exact| <= ~8 ulps
// of max intermediate <= (Qw+40)*2^-20 << S (>=16x margin), and Tc's 2 extra
// roundings are absorbed => v_exact < Tf implies g < Tc. Stage C recomputes
// EXACT keys for all candidates and ranks them — the 17 smallest of any
// superset of the true top-17 are the true top-17 => output bit-identical.
__global__ __launch_bounds__(256) void k_knn(const float4* __restrict__ posf, int* __restrict__ knn){
#pragma clang fp contract(off)
  __shared__ ushort_t sjl[QB][CAP5];   // 4096 B: candidate j per query
  __shared__ u64 kw[4][CAP5];          // 8192 B: per-wave key scratch
  __shared__ int scnt[QB];
  __shared__ uint sut[QB];
  int tid = threadIdx.x;
  int lane = tid & 63;
  int wave = tid >> 6;
  int qbase = blockIdx.x * QB;
  int jbase = (qbase >> 12) << 12;
  if (tid < QB){ scnt[tid] = 0; sut[tid] = 0xFFFFFFFFu; }
  __syncthreads();
  // queries (wave-uniform -> SGPRs)
  float4 Q[QB];
  #pragma unroll
  for (int q = 0; q < QB; ++q) Q[q] = posf[qbase + q];
  // ---- stage A: full-scan per-lane minima of g = pw - 2*dot (r5-r7-proven) ----
  float lmg[QB];
  #pragma unroll
  for (int q = 0; q < QB; ++q) lmg[q] = 3.0e38f;
  for (int s = 0; s < 16; ++s){
    float4 p = posf[jbase + s*256 + tid];
    float px2 = -2.0f*p.x, py2 = -2.0f*p.y, pz2 = -2.0f*p.z;  // exact scaling
    #pragma unroll
    for (int q = 0; q < QB; ++q){
      float g = __builtin_fmaf(Q[q].x, px2, __builtin_fmaf(Q[q].y, py2,
                __builtin_fmaf(Q[q].z, pz2, p.w)));
      lmg[q] = fminf(lmg[q], g);
    }
  }
  uint lmb[QB];
  #pragma unroll
  for (int q = 0; q < QB; ++q)
    lmb[q] = __float_as_uint(fmaxf(lmg[q] + Q[q].w, 0.0f)); // nonneg: uint order == float order
  // ---- interleaved threshold search: 12 iters, all QB queries per iter ----
  int lo[QB], hi[QB];
  #pragma unroll
  for (int q = 0; q < QB; ++q){ lo[q] = 0; hi[q] = 4095; }
  for (int it = 0; it < 12; ++it){
    #pragma unroll
    for (int q = 0; q < QB; ++q){
      int mid = (lo[q] + hi[q]) >> 1;
      uint T = (uint)(mid+1) << 19;
      u64 bal = __ballot(lmb[q] < T);
      bool c = __popcll(bal) >= 17;
      hi[q] = c ? mid : hi[q];
      lo[q] = c ? lo[q] : mid + 1;
    }
  }
  #pragma unroll
  for (int q = 0; q < QB; ++q){
    if (lane == 0) atomicMin(&sut[q], (uint)(lo[q]+2) << 19);  // +1 granule: fma-eps safety
  }
  __syncthreads();
  // cheap-collect thresholds (float domain, slack-inflated superset)
  float Tc[QB];
  #pragma unroll
  for (int q = 0; q < QB; ++q){
    float Tf = __uint_as_float(sut[q]);
    float S  = (Q[q].w + 16.0f) * 6.103515625e-05f;   // 2^-14
    Tc[q] = (Tf + S) - Q[q].w;
  }
  // ---- stage B: full scan, CHEAP g-filter (4 ops/pair), store j only ----
  for (int s = 0; s < 16; ++s){
    int j = s*256 + tid;
    float4 p = posf[jbase + j];
    float px2 = -2.0f*p.x, py2 = -2.0f*p.y, pz2 = -2.0f*p.z;
    #pragma unroll
    for (int q = 0; q < QB; ++q){
      float g = __builtin_fmaf(Q[q].x, px2, __builtin_fmaf(Q[q].y, py2,
                __builtin_fmaf(Q[q].z, pz2, p.w)));
      if (g < Tc[q]){
        int pc = atomicAdd(&scnt[q], 1);
        if (pc < CAP5) sjl[q][pc] = (ushort_t)j;
      }
    }
  }
  __syncthreads();
  // ---- stage C: rebuild EXACT keys per query, exact rank (wave-private) ----
  for (int q = wave; q < QB; q += 4){
    int cnt = scnt[q]; if (cnt > CAP5) cnt = CAP5;
    float4 Qq = posf[qbase + q];    // wave-uniform reload (avoids runtime-idx spill)
    for (int base = 0; base < cnt; base += 64){
      int ci = base + lane;
      if (ci < cnt){
        int j = sjl[q][ci];
        float4 p = posf[jbase + j];
        float ax = Qq.x*p.x; float ay = Qq.y*p.y; float az = Qq.z*p.z;
        float dot = (ax + ay) + az;               // match np einsum order
        float t  = Qq.w + p.w;
        float v  = t - 2.0f*dot;                  // bit-identical exact keys
        uint w = __float_as_uint(v);
        uint sd = w ^ ((w & 0x80000000u) ? 0xFFFFFFFFu : 0x80000000u); // signed monotone map
        kw[wave][ci] = (((u64)sd) << 32) | (uint)j;
      }
    }
    WAVE_SYNC();
    for (int base = 0; base < cnt; base += 64){
      int ci = base + lane;
      u64 mykey = (ci < cnt) ? kw[wave][ci] : ~0ull;
      int r = 0;
      for (int i = 0; i < cnt; ++i) r += (kw[wave][i] < mykey) ? 1 : 0;
      if (ci < cnt && r >= 1 && r <= 16)
        knn[(qbase + q)*16 + (r-1)] = (int)(mykey & 0xFFFFFFFFu);
    }
    WAVE_SYNC();   // keys of this query consumed before next query overwrites
  }
}

// ---------------- kernel W: weight prep ----------------
// Wtiles: 24 tiles x 1024 elems (2KB each), pre-swizzled SWZE image.
// tiles 0..3 = A1[nt]; 4..11 = B2[nt*2+kk]; 12..23 = C3[nt*3+kk].
__global__ __launch_bounds__(256) void k_wprep(const void* __restrict__ Wf, const void* __restrict__ bfv,
                        const void* __restrict__ Wm1, const void* __restrict__ bm1,
                        const void* __restrict__ Wm2, const void* __restrict__ bm2,
                        const void* __restrict__ Wl, const void* __restrict__ bl,
                        ushort_t* __restrict__ WcatT, float* __restrict__ biasT,
                        ushort_t* __restrict__ Wtiles,
                        const int* __restrict__ flag){
  int f32 = *flag;
  int id = blockIdx.x*256 + threadIdx.x;
  if (id < 40960){
    int n = id >> 7, k = id & 127;
    float v;
    if (n < 64)       v = ldin(Wf, (long)k*64 + n, f32) - ldin(Wf, (long)(256+k)*64 + n, f32);
    else if (n < 128) v = ldin(Wf, (long)(128+k)*64 + (n-64), f32) + ldin(Wf, (long)(256+k)*64 + (n-64), f32);
    else if (n < 192) v = ldin(Wm1, (long)(64+k)*64 + (n-128), f32);
    else if (n < 256) v = ldin(Wm2, (long)(128+k)*64 + (n-192), f32);
    else              v = ldin(Wl, (long)(192+k)*64 + (n-256), f32);
    WcatT[id] = f2bf(v);
  } else if (id < 41280){
    int n = id - 40960;
    float bv;
    if (n < 64)       bv = ldin(bfv, n, f32);
    else if (n < 128) bv = 0.0f;
    else if (n < 192) bv = ldin(bm1, n-128, f32);
    else if (n < 256) bv = ldin(bm2, n-192, f32);
    else              bv = ldin(bl, n-256, f32);
    biasT[n] = bv;
  } else if (id < 65856){      // Wtiles: 24576 elems
    int t2 = id - 41280;
    int tile = t2 >> 10;
    int r    = (t2 >> 6) & 15;
    int ep   = t2 & 63;
    int kl   = ep ^ ((r & 7) << 3);
    float v;
    if (tile < 4){
      int n = tile*16 + r;
      v = ldin(Wm1, (long)kl*64 + n, f32);
    } else if (tile < 12){
      int u = tile - 4; int n = (u >> 1)*16 + r; int k = (u & 1)*64 + kl;
      v = ldin(Wm2, (long)k*64 + n, f32);
    } else {
      int u = tile - 12; int n = (u / 3)*16 + r; int k = (u % 3)*64 + kl;
      v = ldin(Wl, (long)k*64 + n, f32);
    }
    Wtiles[t2] = f2bf(v);
  }
}

// ---------------- kernel 2: P = X @ Wcat + bias  (bf16 out, rows 32768 x 320) ----------------
__global__ __launch_bounds__(256) void k_pgemm(const void* __restrict__ xv, const ushort_t* __restrict__ WcatT,
                                               const float* __restrict__ biasT, ushort_t* __restrict__ P,
                                               const int* __restrict__ flag){
  int f32 = *flag;
  int wave = threadIdx.x >> 6, lane = threadIdx.x & 63;
  int rowbase = blockIdx.x*64 + wave*16;
  int quad = lane >> 4, col = lane & 15;
  floatx4 acc[20];
  #pragma unroll
  for (int i = 0; i < 20; ++i) acc[i] = (floatx4){0.f,0.f,0.f,0.f};
  #pragma unroll
  for (int kk = 0; kk < 4; ++kk){
    int k = kk*32 + quad*8;
    short8 a;
    if (f32){
      const float* xf = (const float*)xv + (long)(rowbase + col)*128 + k;
      #pragma unroll
      for (int i = 0; i < 8; ++i) a[i] = (short)f2bf(xf[i]);
    } else {
      a = *(const short8*)((const ushort_t*)xv + (long)(rowbase + col)*128 + k);
    }
    #pragma unroll
    for (int nt = 0; nt < 20; ++nt){
      short8 bb = *(const short8*)(WcatT + (nt*16 + col)*128 + k);
      acc[nt] = __builtin_amdgcn_mfma_f32_16x16x32_bf16(a, bb, acc[nt], 0, 0, 0);
    }
  }
  #pragma unroll
  for (int nt = 0; nt < 20; ++nt){
    float bv = biasT[nt*16 + col];
    #pragma unroll
    for (int r = 0; r < 4; ++r){
      int m = quad*4 + r;
      P[(long)(rowbase + m)*320 + nt*16 + col] = f2bf(acc[nt][r] + bv);
    }
  }
}

// ---------------- kernel 3: per-edge chain + max over K ----------------
// v9 = r7 structure + full next-query prefetch: gather rows, Q-row, the 12
// u-values, and the 2 x-row values for query iq+1 all issue during query iq's
// compute, before the WAVE_SYNCs that would pin them (asm memory clobber
// blocks compiler hoisting — prefetch must be explicit). Math bit-identical.
__global__ __launch_bounds__(512) void k_edge(const void* __restrict__ x, const ushort_t* __restrict__ P,
                                              const int* __restrict__ knn,
                                              const ushort_t* __restrict__ Wg, void* __restrict__ out,
                                              const int* __restrict__ flag){
  __shared__ __align__(16) ushort_t wlds[12*1024];     // 24KB: A1 + B2
  __shared__ __align__(16) ushort_t hb[8][3][1024];    // 48KB: h1,h2,h3 per wave
  int f32 = *flag;
  int tid = threadIdx.x;
  int wave = tid >> 6, lane = tid & 63;
  int quad = lane >> 4, col = lane & 15;
  int qid0 = blockIdx.x*(8*NQE) + wave*NQE;
  int b = qid0 >> 12;                        // all NQE queries in same batch (64 | 4096)
  const ushort_t* Pb = P + ((long)(b<<12))*320;
  int e4 = lane >> 2, cg = lane & 3;

  // preload all neighbor indices (independent of LDS staging — issue first)
  int idxv[NQE];
  #pragma unroll
  for (int iq = 0; iq < NQE; ++iq)
    idxv[iq] = knn[(qid0+iq)*16 + e4] & (NP - 1);   // mask: corrupt idx stays in-bounds
  // prologue prefetch for query 0 (overlaps the staging barrier)
  short8 nk0 = *(const short8*)(Pb + (long)idxv[0]*320 + 64 + cg*16);
  short8 nk1 = *(const short8*)(Pb + (long)idxv[0]*320 + 64 + cg*16 + 8);
  short8 nq0 = *(const short8*)(P + (long)qid0*320 + cg*16);
  short8 nq1 = *(const short8*)(P + (long)qid0*320 + cg*16 + 8);
  float nu1[4], nu2[4], nu3[4];
  #pragma unroll
  for (int nt = 0; nt < 4; ++nt){
    nu1[nt] = bf2f(P[(long)qid0*320 + 128 + nt*16 + col]);
    nu2[nt] = bf2f(P[(long)qid0*320 + 192 + nt*16 + col]);
    nu3[nt] = bf2f(P[(long)qid0*320 + 256 + nt*16 + col]);
  }
  float nx0 = ldin(x, (long)qid0*128 + lane, f32);
  float nx1 = ldin(x, (long)qid0*128 + 64 + lane, f32);

  // stage A1+B2: linear copy of the pre-swizzled image (conflict-free b128)
  #pragma unroll
  for (int i = 0; i < 3; ++i){
    int e = (i*512 + tid) << 3;
    *(short8*)(wlds + e) = *(const short8*)(Wg + e);
  }
  __syncthreads();
  const ushort_t* wA  = wlds;                // + nt*1024
  const ushort_t* wB  = wlds + 4*1024;       // + (nt*2+kk)*1024
  const ushort_t* wCg = Wg + 12*1024;        // + (nt*3+kk)*1024 (global, L1-hot)
  ushort_t* h1p = hb[wave][0];
  ushort_t* h2p = hb[wave][1];
  ushort_t* h3p = hb[wave][2];

  #pragma unroll
  for (int iq = 0; iq < NQE; ++iq){
    int qid = qid0 + iq;
    long outb = (long)qid*384;

    // capture current query's prefetched values
    short8 k0 = nk0, k1 = nk1, q0 = nq0, q1 = nq1;
    float u1v[4], u2v[4], u3v[4];
    #pragma unroll
    for (int nt = 0; nt < 4; ++nt){ u1v[nt] = nu1[nt]; u2v[nt] = nu2[nt]; u3v[nt] = nu3[nt]; }
    float x0 = nx0, x1 = nx1;

    // prefetch next query (independent of current compute)
    if (iq + 1 < NQE){
      long pn = (long)(qid+1)*320;
      nk0 = *(const short8*)(Pb + (long)idxv[iq+1]*320 + 64 + cg*16);
      nk1 = *(const short8*)(Pb + (long)idxv[iq+1]*320 + 64 + cg*16 + 8);
      nq0 = *(const short8*)(P + pn + cg*16);
      nq1 = *(const short8*)(P + pn + cg*16 + 8);
      #pragma unroll
      for (int nt = 0; nt < 4; ++nt){
        nu1[nt] = bf2f(P[pn + 128 + nt*16 + col]);
        nu2[nt] = bf2f(P[pn + 192 + nt*16 + col]);
        nu3[nt] = bf2f(P[pn + 256 + nt*16 + col]);
      }
      nx0 = ldin(x, (long)(qid+1)*128 + lane, f32);
      nx1 = ldin(x, (long)(qid+1)*128 + 64 + lane, f32);
    }

    // h1 = relu(q_i + k_j): lane -> edge e=e4, col-group cg
    {
      short8 h0, h1r;
      #pragma unroll
      for (int i = 0; i < 8; ++i){
        float v = fmaxf(bf2f((ushort_t)q0[i]) + bf2f((ushort_t)k0[i]), 0.0f);
        h0[i] = (short)f2bf(v);
        float w = fmaxf(bf2f((ushort_t)q1[i]) + bf2f((ushort_t)k1[i]), 0.0f);
        h1r[i] = (short)f2bf(w);
      }
      *(short8*)(h1p + SWZE(e4, cg*16))     = h0;
      *(short8*)(h1p + SWZE(e4, cg*16 + 8)) = h1r;
    }
    WAVE_SYNC();

    // layer 2: h2 = relu(h1 @ A1 + u1)
    floatx4 acc2[4];
    #pragma unroll
    for (int nt = 0; nt < 4; ++nt) acc2[nt] = (floatx4){0.f,0.f,0.f,0.f};
    #pragma unroll
    for (int kk = 0; kk < 2; ++kk){
      int k = kk*32 + quad*8;
      short8 a = *(const short8*)(h1p + SWZE(col, k));
      #pragma unroll
      for (int nt = 0; nt < 4; ++nt){
        short8 bb = *(const short8*)(wA + nt*1024 + SWZE(col, k));
        acc2[nt] = __builtin_amdgcn_mfma_f32_16x16x32_bf16(a, bb, acc2[nt], 0, 0, 0);
      }
    }
    #pragma unroll
    for (int nt = 0; nt < 4; ++nt){
      float v0 = fmaxf(acc2[nt][0] + u1v[nt], 0.0f);
      float v1 = fmaxf(acc2[nt][1] + u1v[nt], 0.0f);
      float v2 = fmaxf(acc2[nt][2] + u1v[nt], 0.0f);
      float v3 = fmaxf(acc2[nt][3] + u1v[nt], 0.0f);
      h2p[SWZE(quad*4+0, nt*16+col)] = f2bf(v0);
      h2p[SWZE(quad*4+1, nt*16+col)] = f2bf(v1);
      h2p[SWZE(quad*4+2, nt*16+col)] = f2bf(v2);
      h2p[SWZE(quad*4+3, nt*16+col)] = f2bf(v3);
      // store-early max: f2bf monotone => f2bf(max)==max(f2bf)
      float m2 = fmaxf(fmaxf(v0, v1), fmaxf(v2, v3));
      m2 = fmaxf(m2, __shfl_xor(m2, 16, 64));
      m2 = fmaxf(m2, __shfl_xor(m2, 32, 64));
      if (lane < 16) stout(out, outb + 128 + nt*16 + lane, bf2f(f2bf(m2)), f32);
    }
    WAVE_SYNC();

    // layer 3: h3 = relu([h2|h1] @ B2 + u2)
    floatx4 acc3[4];
    #pragma unroll
    for (int nt = 0; nt < 4; ++nt) acc3[nt] = (floatx4){0.f,0.f,0.f,0.f};
    #pragma unroll
    for (int kk = 0; kk < 4; ++kk){
      int kg = kk*32 + quad*8;
      const ushort_t* src = (kk < 2) ? h2p : h1p;
      int kl = (kk < 2) ? kg : (kg - 64);
      short8 a = *(const short8*)(src + SWZE(col, kl));
      #pragma unroll
      for (int nt = 0; nt < 4; ++nt){
        short8 bb = *(const short8*)(wB + (nt*2 + (kg>>6))*1024 + SWZE(col, kg & 63));
        acc3[nt] = __builtin_amdgcn_mfma_f32_16x16x32_bf16(a, bb, acc3[nt], 0, 0, 0);
      }
    }
    #pragma unroll
    for (int nt = 0; nt < 4; ++nt){
      float v0 = fmaxf(acc3[nt][0] + u2v[nt], 0.0f);
      float v1 = fmaxf(acc3[nt][1] + u2v[nt], 0.0f);
      float v2 = fmaxf(acc3[nt][2] + u2v[nt], 0.0f);
      float v3 = fmaxf(acc3[nt][3] + u2v[nt], 0.0f);
      h3p[SWZE(quad*4+0, nt*16+col)] = f2bf(v0);
      h3p[SWZE(quad*4+1, nt*16+col)] = f2bf(v1);
      h3p[SWZE(quad*4+2, nt*16+col)] = f2bf(v2);
      h3p[SWZE(quad*4+3, nt*16+col)] = f2bf(v3);
      float m3 = fmaxf(fmaxf(v0, v1), fmaxf(v2, v3));
      m3 = fmaxf(m3, __shfl_xor(m3, 16, 64));
      m3 = fmaxf(m3, __shfl_xor(m3, 32, 64));
      if (lane < 16) stout(out, outb + 64 + nt*16 + lane, bf2f(f2bf(m3)), f32);
    }
    WAVE_SYNC();

    // layer 4: o = [h3|h2|h1] @ C3 + u3  (no relu; C3 from global/L1)
    floatx4 acc4[4];
    #pragma unroll
    for (int nt = 0; nt < 4; ++nt) acc4[nt] = (floatx4){0.f,0.f,0.f,0.f};
    #pragma unroll
    for (int kk = 0; kk < 6; ++kk){
      int kg = kk*32 + quad*8;
      const ushort_t* src = (kk < 2) ? h3p : ((kk < 4) ? h2p : h1p);
      int kl = (kk < 2) ? kg : ((kk < 4) ? (kg - 64) : (kg - 128));
      short8 a = *(const short8*)(src + SWZE(col, kl));
      #pragma unroll
      for (int nt = 0; nt < 4; ++nt){
        short8 bb = *(const short8*)(wCg + (nt*3 + (kg>>6))*1024 + SWZE(col, kg & 63));
        acc4[nt] = __builtin_amdgcn_mfma_f32_16x16x32_bf16(a, bb, acc4[nt], 0, 0, 0);
      }
    }
    #pragma unroll
    for (int nt = 0; nt < 4; ++nt){
      float m0 = fmaxf(fmaxf(acc4[nt][0], acc4[nt][1]), fmaxf(acc4[nt][2], acc4[nt][3])) + u3v[nt];
      m0 = fmaxf(m0, __shfl_xor(m0, 16, 64));
      m0 = fmaxf(m0, __shfl_xor(m0, 32, 64));
      if (lane < 16) stout(out, outb + nt*16 + lane, m0, f32);
    }
    {
      ushort_t mx1 = 0;
      #pragma unroll
      for (int m = 0; m < 16; ++m){
        ushort_t v1u = h1p[SWZE(m, lane)]; if (v1u > mx1) mx1 = v1u;
      }
      // post-relu bf16 >= 0: bit compare == float compare
      stout(out, outb + 192 + lane, bf2f(mx1), f32);
      stout(out, outb + 256 + lane,      x0, f32);
      stout(out, outb + 256 + 64 + lane, x1, f32);
    }
    WAVE_SYNC();   // order h-tile reads of this query before next query's writes
  }
}

extern "C" void kernel_launch(void* const* d_in, const int* in_sizes, int n_in,
                              void* d_out, int out_size, void* d_ws, size_t ws_size,
                              hipStream_t stream){
  const void* x   = d_in[0];
  const void* pos = d_in[1];
  const void* Wf  = d_in[2];
  const void* bfv = d_in[3];
  const void* Wm1 = d_in[4];
  const void* bm1 = d_in[5];
  const void* Wm2 = d_in[6];
  const void* bm2 = d_in[7];
  const void* Wl  = d_in[8];
  const void* bl  = d_in[9];
  char* ws = (char*)d_ws;
  float4*   posf   = (float4*)(ws + 0);                 // 524288 B
  int*      knn    = (int*)(ws + 524288);               // 2097152 B
  ushort_t* P      = (ushort_t*)(ws + 2621440);         // 20971520 B
  ushort_t* WcatT  = (ushort_t*)(ws + 23592960);        // 81920 B
  float*    biasT  = (float*)(ws + 23674880);           // 1280 B
  ushort_t* Wtiles = (ushort_t*)(ws + 23676160);        // 49152 B (pre-swizzled SWZE image)
  int*      flag   = (int*)(ws + 23725312);             // 4 B (total ~22.63 MB)

  k_detect<<<1,    256, 0, stream>>>((const uint*)Wf, flag);
  k_posf <<<128,   256, 0, stream>>>(pos, posf, flag);
  k_wprep<<<258,   256, 0, stream>>>(Wf, bfv, Wm1, bm1, Wm2, bm2, Wl, bl, WcatT, biasT, Wtiles, flag);
  k_knn  <<<4096,  256, 0, stream>>>(posf, knn);
  k_pgemm<<<512,   256, 0, stream>>>(x, WcatT, biasT, P, flag);
  k_edge <<<512,   512, 0, stream>>>(x, P, knn, Wtiles, d_out, flag);
}

// Round 9
// 309.818 us; speedup vs baseline: 1.1028x; 1.1028x over previous
//
#include <hip/hip_runtime.h>
#include <hip/hip_bf16.h>

typedef unsigned int uint;
typedef unsigned short ushort_t;
typedef unsigned long long u64;
typedef __attribute__((ext_vector_type(8))) short short8;
typedef __attribute__((ext_vector_type(4))) float floatx4;

#define NB 8
#define NP 4096
#define ND 128
#define NK 16
#define NC 64
#define NPTS 32768   // NB*NP
#define QB 8         // queries per k_knn block (r7-proven)
#define CAP5 256     // per-query candidate j-buffer (cheap filter ~130 max, 2x margin)
#define NQE 8        // sequential queries per k_edge wave

__device__ __forceinline__ float bf2f(ushort_t h){ return __uint_as_float(((uint)h)<<16); }
__device__ __forceinline__ ushort_t f2bf(float f){
  uint u = __float_as_uint(f);
  u = u + 0x7FFFu + ((u>>16)&1u);
  return (ushort_t)(u>>16);
}
// dtype-polymorphic input load (f32=1: fp32 array, f32=0: bf16 array)
__device__ __forceinline__ float ldin(const void* p, long i, int f32){
  return f32 ? ((const float*)p)[i] : bf2f(((const ushort_t*)p)[i]);
}
// dtype-polymorphic output store
__device__ __forceinline__ void stout(void* o, long i, float v, int f32){
  if (f32) ((float*)o)[i] = v; else ((ushort_t*)o)[i] = f2bf(v);
}

// XOR-swizzled LDS element index for 16-row x 64-elem bf16 tiles (128 B rows).
// Keeps 16B alignment for e%8==0; measured conflict-free (BANK_CONFLICT=0, r3-r8).
#define SWZE(row, e) (((row)<<6) + ((e) ^ (((row)&7)<<3)))
// Intra-wave LDS write->read fence (wave-private buffers; DS ops of one wave
// execute in order; asm memory clobber pins compiler ordering). r4-r8-proven.
#define WAVE_SYNC() asm volatile("s_waitcnt lgkmcnt(0)" ::: "memory")

// ---------------- kernel D: detect input dtype ----------------
__global__ __launch_bounds__(256) void k_detect(const uint* __restrict__ w, int* __restrict__ flag){
  __shared__ int cnt;
  if (threadIdx.x == 0) cnt = 0;
  __syncthreads();
  int c = 0;
  for (int i = threadIdx.x; i < 512; i += 256){
    uint u = w[i];
    uint e = (u >> 7) & 0xFFu;
    c += (e >= 100u && e < 128u) ? 1 : 0;
  }
  atomicAdd(&cnt, c);
  __syncthreads();
  if (threadIdx.x == 0) *flag = (cnt < 256) ? 1 : 0;   // 1 => fp32 inputs/outputs
}

// ---------------- kernel 0: pos -> float4 {x,y,z,sq} ----------------
__global__ __launch_bounds__(256) void k_posf(const void* __restrict__ pos, float4* __restrict__ posf,
                                              const int* __restrict__ flag){
#pragma clang fp contract(off)
  int f32 = *flag;
  int p = blockIdx.x*256 + threadIdx.x;
  if (p >= NPTS) return;
  float x = ldin(pos, (long)p*3+0, f32);
  float y = ldin(pos, (long)p*3+1, f32);
  float z = ldin(pos, (long)p*3+2, f32);
  float px = x*x; float py = y*y; float pz = z*z;
  float sq = (px + py) + pz;   // match np.sum(pos*pos,-1) sequential order
  posf[p] = make_float4(x, y, z, sq);
}

// ---------------- kernel 1: exact 17-NN, QB queries per block ----------------
// v9 (r8-passed): r7 threshold logic verbatim + cheap-collect stage B
// (g < Tc superset filter, 4 ops/pair); stage C recomputes EXACT keys and
// ranks -> output bit-identical to the r6/r7-proven exact selection.
__global__ __launch_bounds__(256) void k_knn(const float4* __restrict__ posf, int* __restrict__ knn){
#pragma clang fp contract(off)
  __shared__ ushort_t sjl[QB][CAP5];   // 4096 B: candidate j per query
  __shared__ u64 kw[4][CAP5];          // 8192 B: per-wave key scratch
  __shared__ int scnt[QB];
  __shared__ uint sut[QB];
  int tid = threadIdx.x;
  int lane = tid & 63;
  int wave = tid >> 6;
  int qbase = blockIdx.x * QB;
  int jbase = (qbase >> 12) << 12;
  if (tid < QB){ scnt[tid] = 0; sut[tid] = 0xFFFFFFFFu; }
  __syncthreads();
  // queries (wave-uniform -> SGPRs)
  float4 Q[QB];
  #pragma unroll
  for (int q = 0; q < QB; ++q) Q[q] = posf[qbase + q];
  // ---- stage A: full-scan per-lane minima of g = pw - 2*dot (r5-r8-proven) ----
  float lmg[QB];
  #pragma unroll
  for (int q = 0; q < QB; ++q) lmg[q] = 3.0e38f;
  for (int s = 0; s < 16; ++s){
    float4 p = posf[jbase + s*256 + tid];
    float px2 = -2.0f*p.x, py2 = -2.0f*p.y, pz2 = -2.0f*p.z;  // exact scaling
    #pragma unroll
    for (int q = 0; q < QB; ++q){
      float g = __builtin_fmaf(Q[q].x, px2, __builtin_fmaf(Q[q].y, py2,
                __builtin_fmaf(Q[q].z, pz2, p.w)));
      lmg[q] = fminf(lmg[q], g);
    }
  }
  uint lmb[QB];
  #pragma unroll
  for (int q = 0; q < QB; ++q)
    lmb[q] = __float_as_uint(fmaxf(lmg[q] + Q[q].w, 0.0f)); // nonneg: uint order == float order
  // ---- interleaved threshold search: 12 iters, all QB queries per iter ----
  int lo[QB], hi[QB];
  #pragma unroll
  for (int q = 0; q < QB; ++q){ lo[q] = 0; hi[q] = 4095; }
  for (int it = 0; it < 12; ++it){
    #pragma unroll
    for (int q = 0; q < QB; ++q){
      int mid = (lo[q] + hi[q]) >> 1;
      uint T = (uint)(mid+1) << 19;
      u64 bal = __ballot(lmb[q] < T);
      bool c = __popcll(bal) >= 17;
      hi[q] = c ? mid : hi[q];
      lo[q] = c ? lo[q] : mid + 1;
    }
  }
  #pragma unroll
  for (int q = 0; q < QB; ++q){
    if (lane == 0) atomicMin(&sut[q], (uint)(lo[q]+2) << 19);  // +1 granule: fma-eps safety
  }
  __syncthreads();
  // cheap-collect thresholds (float domain, slack-inflated superset)
  float Tc[QB];
  #pragma unroll
  for (int q = 0; q < QB; ++q){
    float Tf = __uint_as_float(sut[q]);
    float S  = (Q[q].w + 16.0f) * 6.103515625e-05f;   // 2^-14
    Tc[q] = (Tf + S) - Q[q].w;
  }
  // ---- stage B: full scan, CHEAP g-filter (4 ops/pair), store j only ----
  for (int s = 0; s < 16; ++s){
    int j = s*256 + tid;
    float4 p = posf[jbase + j];
    float px2 = -2.0f*p.x, py2 = -2.0f*p.y, pz2 = -2.0f*p.z;
    #pragma unroll
    for (int q = 0; q < QB; ++q){
      float g = __builtin_fmaf(Q[q].x, px2, __builtin_fmaf(Q[q].y, py2,
                __builtin_fmaf(Q[q].z, pz2, p.w)));
      if (g < Tc[q]){
        int pc = atomicAdd(&scnt[q], 1);
        if (pc < CAP5) sjl[q][pc] = (ushort_t)j;
      }
    }
  }
  __syncthreads();
  // ---- stage C: rebuild EXACT keys per query, exact rank (wave-private) ----
  for (int q = wave; q < QB; q += 4){
    int cnt = scnt[q]; if (cnt > CAP5) cnt = CAP5;
    float4 Qq = posf[qbase + q];    // wave-uniform reload (avoids runtime-idx spill)
    for (int base = 0; base < cnt; base += 64){
      int ci = base + lane;
      if (ci < cnt){
        int j = sjl[q][ci];
        float4 p = posf[jbase + j];
        float ax = Qq.x*p.x; float ay = Qq.y*p.y; float az = Qq.z*p.z;
        float dot = (ax + ay) + az;               // match np einsum order
        float t  = Qq.w + p.w;
        float v  = t - 2.0f*dot;                  // bit-identical exact keys
        uint w = __float_as_uint(v);
        uint sd = w ^ ((w & 0x80000000u) ? 0xFFFFFFFFu : 0x80000000u); // signed monotone map
        kw[wave][ci] = (((u64)sd) << 32) | (uint)j;
      }
    }
    WAVE_SYNC();
    for (int base = 0; base < cnt; base += 64){
      int ci = base + lane;
      u64 mykey = (ci < cnt) ? kw[wave][ci] : ~0ull;
      int r = 0;
      for (int i = 0; i < cnt; ++i) r += (kw[wave][i] < mykey) ? 1 : 0;
      if (ci < cnt && r >= 1 && r <= 16)
        knn[(qbase + q)*16 + (r-1)] = (int)(mykey & 0xFFFFFFFFu);
    }
    WAVE_SYNC();   // keys of this query consumed before next query overwrites
  }
}

// ---------------- kernel W: weight prep ----------------
// Wtiles: 24 tiles x 1024 elems (2KB each), pre-swizzled SWZE image.
// tiles 0..3 = A1[nt]; 4..11 = B2[nt*2+kk]; 12..23 = C3[nt*3+kk].
__global__ __launch_bounds__(256) void k_wprep(const void* __restrict__ Wf, const void* __restrict__ bfv,
                        const void* __restrict__ Wm1, const void* __restrict__ bm1,
                        const void* __restrict__ Wm2, const void* __restrict__ bm2,
                        const void* __restrict__ Wl, const void* __restrict__ bl,
                        ushort_t* __restrict__ WcatT, float* __restrict__ biasT,
                        ushort_t* __restrict__ Wtiles,
                        const int* __restrict__ flag){
  int f32 = *flag;
  int id = blockIdx.x*256 + threadIdx.x;
  if (id < 40960){
    int n = id >> 7, k = id & 127;
    float v;
    if (n < 64)       v = ldin(Wf, (long)k*64 + n, f32) - ldin(Wf, (long)(256+k)*64 + n, f32);
    else if (n < 128) v = ldin(Wf, (long)(128+k)*64 + (n-64), f32) + ldin(Wf, (long)(256+k)*64 + (n-64), f32);
    else if (n < 192) v = ldin(Wm1, (long)(64+k)*64 + (n-128), f32);
    else if (n < 256) v = ldin(Wm2, (long)(128+k)*64 + (n-192), f32);
    else              v = ldin(Wl, (long)(192+k)*64 + (n-256), f32);
    WcatT[id] = f2bf(v);
  } else if (id < 41280){
    int n = id - 40960;
    float bv;
    if (n < 64)       bv = ldin(bfv, n, f32);
    else if (n < 128) bv = 0.0f;
    else if (n < 192) bv = ldin(bm1, n-128, f32);
    else if (n < 256) bv = ldin(bm2, n-192, f32);
    else              bv = ldin(bl, n-256, f32);
    biasT[n] = bv;
  } else if (id < 65856){      // Wtiles: 24576 elems
    int t2 = id - 41280;
    int tile = t2 >> 10;
    int r    = (t2 >> 6) & 15;
    int ep   = t2 & 63;
    int kl   = ep ^ ((r & 7) << 3);
    float v;
    if (tile < 4){
      int n = tile*16 + r;
      v = ldin(Wm1, (long)kl*64 + n, f32);
    } else if (tile < 12){
      int u = tile - 4; int n = (u >> 1)*16 + r; int k = (u & 1)*64 + kl;
      v = ldin(Wm2, (long)k*64 + n, f32);
    } else {
      int u = tile - 12; int n = (u / 3)*16 + r; int k = (u % 3)*64 + kl;
      v = ldin(Wl, (long)k*64 + n, f32);
    }
    Wtiles[t2] = f2bf(v);
  }
}

// ---------------- kernel 2: P = X @ Wcat + bias  (bf16 out, rows 32768 x 320) ----------------
__global__ __launch_bounds__(256) void k_pgemm(const void* __restrict__ xv, const ushort_t* __restrict__ WcatT,
                                               const float* __restrict__ biasT, ushort_t* __restrict__ P,
                                               const int* __restrict__ flag){
  int f32 = *flag;
  int wave = threadIdx.x >> 6, lane = threadIdx.x & 63;
  int rowbase = blockIdx.x*64 + wave*16;
  int quad = lane >> 4, col = lane & 15;
  floatx4 acc[20];
  #pragma unroll
  for (int i = 0; i < 20; ++i) acc[i] = (floatx4){0.f,0.f,0.f,0.f};
  #pragma unroll
  for (int kk = 0; kk < 4; ++kk){
    int k = kk*32 + quad*8;
    short8 a;
    if (f32){
      const float* xf = (const float*)xv + (long)(rowbase + col)*128 + k;
      #pragma unroll
      for (int i = 0; i < 8; ++i) a[i] = (short)f2bf(xf[i]);
    } else {
      a = *(const short8*)((const ushort_t*)xv + (long)(rowbase + col)*128 + k);
    }
    #pragma unroll
    for (int nt = 0; nt < 20; ++nt){
      short8 bb = *(const short8*)(WcatT + (nt*16 + col)*128 + k);
      acc[nt] = __builtin_amdgcn_mfma_f32_16x16x32_bf16(a, bb, acc[nt], 0, 0, 0);
    }
  }
  #pragma unroll
  for (int nt = 0; nt < 20; ++nt){
    float bv = biasT[nt*16 + col];
    #pragma unroll
    for (int r = 0; r < 4; ++r){
      int m = quad*4 + r;
      P[(long)(rowbase + m)*320 + nt*16 + col] = f2bf(acc[nt][r] + bv);
    }
  }
}

// ---------------- kernel 3: per-edge chain + max over K ----------------
// r7 version VERBATIM (r8's extended prefetch regressed: VGPR 92, occupancy
// 22.6%, 164 µs vs ~120). 512-thread blocks (8 waves), 512 blocks -> 2
// blocks/CU, one clean round; idx preload + k/q gather prefetch only;
// u-values at iteration top; x in epilogue. C3 from global/L1.
__global__ __launch_bounds__(512) void k_edge(const void* __restrict__ x, const ushort_t* __restrict__ P,
                                              const int* __restrict__ knn,
                                              const ushort_t* __restrict__ Wg, void* __restrict__ out,
                                              const int* __restrict__ flag){
  __shared__ __align__(16) ushort_t wlds[12*1024];     // 24KB: A1 + B2
  __shared__ __align__(16) ushort_t hb[8][3][1024];    // 48KB: h1,h2,h3 per wave
  int f32 = *flag;
  int tid = threadIdx.x;
  int wave = tid >> 6, lane = tid & 63;
  int quad = lane >> 4, col = lane & 15;
  int qid0 = blockIdx.x*(8*NQE) + wave*NQE;
  int b = qid0 >> 12;                        // all NQE queries in same batch (64 | 4096)
  const ushort_t* Pb = P + ((long)(b<<12))*320;
  int e4 = lane >> 2, cg = lane & 3;

  // preload all neighbor indices (independent of LDS staging — issue first)
  int idxv[NQE];
  #pragma unroll
  for (int iq = 0; iq < NQE; ++iq)
    idxv[iq] = knn[(qid0+iq)*16 + e4] & (NP - 1);   // mask: corrupt idx stays in-bounds
  // prologue gather for query 0 (overlaps the staging barrier)
  short8 nk0 = *(const short8*)(Pb + (long)idxv[0]*320 + 64 + cg*16);
  short8 nk1 = *(const short8*)(Pb + (long)idxv[0]*320 + 64 + cg*16 + 8);
  short8 nq0 = *(const short8*)(P + (long)qid0*320 + cg*16);
  short8 nq1 = *(const short8*)(P + (long)qid0*320 + cg*16 + 8);

  // stage A1+B2: linear copy of the pre-swizzled image (conflict-free b128)
  #pragma unroll
  for (int i = 0; i < 3; ++i){
    int e = (i*512 + tid) << 3;
    *(short8*)(wlds + e) = *(const short8*)(Wg + e);
  }
  __syncthreads();
  const ushort_t* wA  = wlds;                // + nt*1024
  const ushort_t* wB  = wlds + 4*1024;       // + (nt*2+kk)*1024
  const ushort_t* wCg = Wg + 12*1024;        // + (nt*3+kk)*1024 (global, L1-hot)
  ushort_t* h1p = hb[wave][0];
  ushort_t* h2p = hb[wave][1];
  ushort_t* h3p = hb[wave][2];

  #pragma unroll
  for (int iq = 0; iq < NQE; ++iq){
    int qid = qid0 + iq;
    const ushort_t* Prow = P + (long)qid*320;
    long outb = (long)qid*384;

    float u1v[4], u2v[4], u3v[4];
    #pragma unroll
    for (int nt = 0; nt < 4; ++nt){
      u1v[nt] = bf2f(Prow[128 + nt*16 + col]);
      u2v[nt] = bf2f(Prow[192 + nt*16 + col]);
      u3v[nt] = bf2f(Prow[256 + nt*16 + col]);
    }

    short8 k0 = nk0, k1 = nk1, q0 = nq0, q1 = nq1;
    // prefetch next query's gather + Q-row (independent of current compute)
    if (iq + 1 < NQE){
      nk0 = *(const short8*)(Pb + (long)idxv[iq+1]*320 + 64 + cg*16);
      nk1 = *(const short8*)(Pb + (long)idxv[iq+1]*320 + 64 + cg*16 + 8);
      nq0 = *(const short8*)(P + (long)(qid+1)*320 + cg*16);
      nq1 = *(const short8*)(P + (long)(qid+1)*320 + cg*16 + 8);
    }

    // h1 = relu(q_i + k_j): lane -> edge e=e4, col-group cg
    {
      short8 h0, h1r;
      #pragma unroll
      for (int i = 0; i < 8; ++i){
        float v = fmaxf(bf2f((ushort_t)q0[i]) + bf2f((ushort_t)k0[i]), 0.0f);
        h0[i] = (short)f2bf(v);
        float w = fmaxf(bf2f((ushort_t)q1[i]) + bf2f((ushort_t)k1[i]), 0.0f);
        h1r[i] = (short)f2bf(w);
      }
      *(short8*)(h1p + SWZE(e4, cg*16))     = h0;
      *(short8*)(h1p + SWZE(e4, cg*16 + 8)) = h1r;
    }
    WAVE_SYNC();

    // layer 2: h2 = relu(h1 @ A1 + u1)
    floatx4 acc2[4];
    #pragma unroll
    for (int nt = 0; nt < 4; ++nt) acc2[nt] = (floatx4){0.f,0.f,0.f,0.f};
    #pragma unroll
    for (int kk = 0; kk < 2; ++kk){
      int k = kk*32 + quad*8;
      short8 a = *(const short8*)(h1p + SWZE(col, k));
      #pragma unroll
      for (int nt = 0; nt < 4; ++nt){
        short8 bb = *(const short8*)(wA + nt*1024 + SWZE(col, k));
        acc2[nt] = __builtin_amdgcn_mfma_f32_16x16x32_bf16(a, bb, acc2[nt], 0, 0, 0);
      }
    }
    #pragma unroll
    for (int nt = 0; nt < 4; ++nt){
      float v0 = fmaxf(acc2[nt][0] + u1v[nt], 0.0f);
      float v1 = fmaxf(acc2[nt][1] + u1v[nt], 0.0f);
      float v2 = fmaxf(acc2[nt][2] + u1v[nt], 0.0f);
      float v3 = fmaxf(acc2[nt][3] + u1v[nt], 0.0f);
      h2p[SWZE(quad*4+0, nt*16+col)] = f2bf(v0);
      h2p[SWZE(quad*4+1, nt*16+col)] = f2bf(v1);
      h2p[SWZE(quad*4+2, nt*16+col)] = f2bf(v2);
      h2p[SWZE(quad*4+3, nt*16+col)] = f2bf(v3);
      // store-early max: f2bf monotone => f2bf(max)==max(f2bf)
      float m2 = fmaxf(fmaxf(v0, v1), fmaxf(v2, v3));
      m2 = fmaxf(m2, __shfl_xor(m2, 16, 64));
      m2 = fmaxf(m2, __shfl_xor(m2, 32, 64));
      if (lane < 16) stout(out, outb + 128 + nt*16 + lane, bf2f(f2bf(m2)), f32);
    }
    WAVE_SYNC();

    // layer 3: h3 = relu([h2|h1] @ B2 + u2)
    floatx4 acc3[4];
    #pragma unroll
    for (int nt = 0; nt < 4; ++nt) acc3[nt] = (floatx4){0.f,0.f,0.f,0.f};
    #pragma unroll
    for (int kk = 0; kk < 4; ++kk){
      int kg = kk*32 + quad*8;
      const ushort_t* src = (kk < 2) ? h2p : h1p;
      int kl = (kk < 2) ? kg : (kg - 64);
      short8 a = *(const short8*)(src + SWZE(col, kl));
      #pragma unroll
      for (int nt = 0; nt < 4; ++nt){
        short8 bb = *(const short8*)(wB + (nt*2 + (kg>>6))*1024 + SWZE(col, kg & 63));
        acc3[nt] = __builtin_amdgcn_mfma_f32_16x16x32_bf16(a, bb, acc3[nt], 0, 0, 0);
      }
    }
    #pragma unroll
    for (int nt = 0; nt < 4; ++nt){
      float v0 = fmaxf(acc3[nt][0] + u2v[nt], 0.0f);
      float v1 = fmaxf(acc3[nt][1] + u2v[nt], 0.0f);
      float v2 = fmaxf(acc3[nt][2] + u2v[nt], 0.0f);
      float v3 = fmaxf(acc3[nt][3] + u2v[nt], 0.0f);
      h3p[SWZE(quad*4+0, nt*16+col)] = f2bf(v0);
      h3p[SWZE(quad*4+1, nt*16+col)] = f2bf(v1);
      h3p[SWZE(quad*4+2, nt*16+col)] = f2bf(v2);
      h3p[SWZE(quad*4+3, nt*16+col)] = f2bf(v3);
      float m3 = fmaxf(fmaxf(v0, v1), fmaxf(v2, v3));
      m3 = fmaxf(m3, __shfl_xor(m3, 16, 64));
      m3 = fmaxf(m3, __shfl_xor(m3, 32, 64));
      if (lane < 16) stout(out, outb + 64 + nt*16 + lane, bf2f(f2bf(m3)), f32);
    }
    WAVE_SYNC();

    // layer 4: o = [h3|h2|h1] @ C3 + u3  (no relu; C3 from global/L1)
    floatx4 acc4[4];
    #pragma unroll
    for (int nt = 0; nt < 4; ++nt) acc4[nt] = (floatx4){0.f,0.f,0.f,0.f};
    #pragma unroll
    for (int kk = 0; kk < 6; ++kk){
      int kg = kk*32 + quad*8;
      const ushort_t* src = (kk < 2) ? h3p : ((kk < 4) ? h2p : h1p);
      int kl = (kk < 2) ? kg : ((kk < 4) ? (kg - 64) : (kg - 128));
      short8 a = *(const short8*)(src + SWZE(col, kl));
      #pragma unroll
      for (int nt = 0; nt < 4; ++nt){
        short8 bb = *(const short8*)(wCg + (nt*3 + (kg>>6))*1024 + SWZE(col, kg & 63));
        acc4[nt] = __builtin_amdgcn_mfma_f32_16x16x32_bf16(a, bb, acc4[nt], 0, 0, 0);
      }
    }
    #pragma unroll
    for (int nt = 0; nt < 4; ++nt){
      float m0 = fmaxf(fmaxf(acc4[nt][0], acc4[nt][1]), fmaxf(acc4[nt][2], acc4[nt][3])) + u3v[nt];
      m0 = fmaxf(m0, __shfl_xor(m0, 16, 64));
      m0 = fmaxf(m0, __shfl_xor(m0, 32, 64));
      if (lane < 16) stout(out, outb + nt*16 + lane, m0, f32);
    }
    {
      ushort_t mx1 = 0;
      #pragma unroll
      for (int m = 0; m < 16; ++m){
        ushort_t v1u = h1p[SWZE(m, lane)]; if (v1u > mx1) mx1 = v1u;
      }
      // post-relu bf16 >= 0: bit compare == float compare
      stout(out, outb + 192 + lane, bf2f(mx1), f32);
      stout(out, outb + 256 + lane,      ldin(x, (long)qid*128 + lane, f32), f32);
      stout(out, outb + 256 + 64 + lane, ldin(x, (long)qid*128 + 64 + lane, f32), f32);
    }
    WAVE_SYNC();   // order h-tile reads of this query before next query's writes
  }
}

extern "C" void kernel_launch(void* const* d_in, const int* in_sizes, int n_in,
                              void* d_out, int out_size, void* d_ws, size_t ws_size,
                              hipStream_t stream){
  const void* x   = d_in[0];
  const void* pos = d_in[1];
  const void* Wf  = d_in[2];
  const void* bfv = d_in[3];
  const void* Wm1 = d_in[4];
  const void* bm1 = d_in[5];
  const void* Wm2 = d_in[6];
  const void* bm2 = d_in[7];
  const void* Wl  = d_in[8];
  const void* bl  = d_in[9];
  char* ws = (char*)d_ws;
  float4*   posf   = (float4*)(ws + 0);                 // 524288 B
  int*      knn    = (int*)(ws + 524288);               // 2097152 B
  ushort_t* P      = (ushort_t*)(ws + 2621440);         // 20971520 B
  ushort_t* WcatT  = (ushort_t*)(ws + 23592960);        // 81920 B
  float*    biasT  = (float*)(ws + 23674880);           // 1280 B
  ushort_t* Wtiles = (ushort_t*)(ws + 23676160);        // 49152 B (pre-swizzled SWZE image)
  int*      flag   = (int*)(ws + 23725312);             // 4 B (total ~22.63 MB)

  k_detect<<<1,    256, 0, stream>>>((const uint*)Wf, flag);
  k_posf <<<128,   256, 0, stream>>>(pos, posf, flag);
  k_wprep<<<258,   256, 0, stream>>>(Wf, bfv, Wm1, bm1, Wm2, bm2, Wl, bl, WcatT, biasT, Wtiles, flag);
  k_knn  <<<4096,  256, 0, stream>>>(posf, knn);
  k_pgemm<<<512,   256, 0, stream>>>(x, WcatT, biasT, P, flag);
  k_edge <<<512,   512, 0, stream>>>(x, P, knn, Wtiles, d_out, flag);
}

// Round 10
// 287.827 us; speedup vs baseline: 1.1870x; 1.0764x over previous
//
#include <hip/hip_runtime.h>
#include <hip/hip_bf16.h>

typedef unsigned int uint;
typedef unsigned short ushort_t;
typedef unsigned long long u64;
typedef __attribute__((ext_vector_type(2))) unsigned long long u64x2;
typedef __attribute__((ext_vector_type(8))) short short8;
typedef __attribute__((ext_vector_type(4))) float floatx4;

#define NB 8
#define NP 4096
#define ND 128
#define NK 16
#define NC 64
#define NPTS 32768   // NB*NP
#define QB 8         // queries per k_knn block (r7-proven)
#define CAP5 256     // per-query candidate j-buffer (cheap filter ~130 max, 2x margin)
#define NQE 8        // sequential queries per k_edge wave

__device__ __forceinline__ float bf2f(ushort_t h){ return __uint_as_float(((uint)h)<<16); }
__device__ __forceinline__ ushort_t f2bf(float f){
  uint u = __float_as_uint(f);
  u = u + 0x7FFFu + ((u>>16)&1u);
  return (ushort_t)(u>>16);
}
// dtype-polymorphic input load (f32=1: fp32 array, f32=0: bf16 array)
__device__ __forceinline__ float ldin(const void* p, long i, int f32){
  return f32 ? ((const float*)p)[i] : bf2f(((const ushort_t*)p)[i]);
}
// dtype-polymorphic output store
__device__ __forceinline__ void stout(void* o, long i, float v, int f32){
  if (f32) ((float*)o)[i] = v; else ((ushort_t*)o)[i] = f2bf(v);
}

// XOR-swizzled LDS element index for 16-row x 64-elem bf16 tiles (128 B rows).
// Keeps 16B alignment for e%8==0; measured conflict-free (BANK_CONFLICT=0, r3-r9).
#define SWZE(row, e) (((row)<<6) + ((e) ^ (((row)&7)<<3)))
// Intra-wave LDS write->read fence (wave-private buffers; DS ops of one wave
// execute in order; asm memory clobber pins compiler ordering). r4-r9-proven.
#define WAVE_SYNC() asm volatile("s_waitcnt lgkmcnt(0)" ::: "memory")

// ---------------- kernel D: detect input dtype ----------------
__global__ __launch_bounds__(256) void k_detect(const uint* __restrict__ w, int* __restrict__ flag){
  __shared__ int cnt;
  if (threadIdx.x == 0) cnt = 0;
  __syncthreads();
  int c = 0;
  for (int i = threadIdx.x; i < 512; i += 256){
    uint u = w[i];
    uint e = (u >> 7) & 0xFFu;
    c += (e >= 100u && e < 128u) ? 1 : 0;
  }
  atomicAdd(&cnt, c);
  __syncthreads();
  if (threadIdx.x == 0) *flag = (cnt < 256) ? 1 : 0;   // 1 => fp32 inputs/outputs
}

// ---------------- kernel 0: pos -> float4 {-2x,-2y,-2z,sq} (posf2 form) ----------------
// sq computed from RAW coords in the proven order; -2x is EXACT (exponent+1,
// sign flip). Consumers reconstruct raw via -0.5f* (exact) => all downstream
// g-values and exact keys bit-identical to r9.
__global__ __launch_bounds__(256) void k_posf(const void* __restrict__ pos, float4* __restrict__ posf,
                                              const int* __restrict__ flag){
#pragma clang fp contract(off)
  int f32 = *flag;
  int p = blockIdx.x*256 + threadIdx.x;
  if (p >= NPTS) return;
  float x = ldin(pos, (long)p*3+0, f32);
  float y = ldin(pos, (long)p*3+1, f32);
  float z = ldin(pos, (long)p*3+2, f32);
  float px = x*x; float py = y*y; float pz = z*z;
  float sq = (px + py) + pz;   // match np.sum(pos*pos,-1) sequential order
  posf[p] = make_float4(-2.0f*x, -2.0f*y, -2.0f*z, sq);
}

// ---------------- kernel 1: exact 17-NN, QB queries per block ----------------
// v10 = r9 logic with (a) posf2 input: per-point -2* prep eliminated (queries
// reconstruct raw via exact -0.5f*), g-values bit-identical; (b) rank loop
// reads keys PAIRED via ds_read_b128 (uniform-address broadcast reads halved
// — the r9 counter analysis flagged the rank loop's ~780 b64 broadcasts/wave
// as the non-VALU limiter). Same comparisons, same sum, same output.
__global__ __launch_bounds__(256) void k_knn(const float4* __restrict__ posf, int* __restrict__ knn){
#pragma clang fp contract(off)
  __shared__ ushort_t sjl[QB][CAP5];             // 4096 B: candidate j per query
  __shared__ __align__(16) u64 kw[4][CAP5];      // 8192 B: per-wave key scratch
  __shared__ int scnt[QB];
  __shared__ uint sut[QB];
  int tid = threadIdx.x;
  int lane = tid & 63;
  int wave = tid >> 6;
  int qbase = blockIdx.x * QB;
  int jbase = (qbase >> 12) << 12;
  if (tid < QB){ scnt[tid] = 0; sut[tid] = 0xFFFFFFFFu; }
  __syncthreads();
  // queries: posf2 form -> reconstruct raw coords (exact -0.5f*), keep sq
  float4 Qr[QB];   // raw x,y,z in .x/.y/.z ; sq in .w
  #pragma unroll
  for (int q = 0; q < QB; ++q){
    float4 q2 = posf[qbase + q];
    Qr[q] = make_float4(-0.5f*q2.x, -0.5f*q2.y, -0.5f*q2.z, q2.w);
  }
  // ---- stage A: full-scan per-lane minima of g = pw - 2*dot ----
  float lmg[QB];
  #pragma unroll
  for (int q = 0; q < QB; ++q) lmg[q] = 3.0e38f;
  for (int s = 0; s < 16; ++s){
    float4 p2 = posf[jbase + s*256 + tid];       // (-2x,-2y,-2z,sq)
    #pragma unroll
    for (int q = 0; q < QB; ++q){
      float g = __builtin_fmaf(Qr[q].x, p2.x, __builtin_fmaf(Qr[q].y, p2.y,
                __builtin_fmaf(Qr[q].z, p2.z, p2.w)));
      lmg[q] = fminf(lmg[q], g);
    }
  }
  uint lmb[QB];
  #pragma unroll
  for (int q = 0; q < QB; ++q)
    lmb[q] = __float_as_uint(fmaxf(lmg[q] + Qr[q].w, 0.0f)); // nonneg: uint order == float order
  // ---- interleaved threshold search: 12 iters, all QB queries per iter ----
  int lo[QB], hi[QB];
  #pragma unroll
  for (int q = 0; q < QB; ++q){ lo[q] = 0; hi[q] = 4095; }
  for (int it = 0; it < 12; ++it){
    #pragma unroll
    for (int q = 0; q < QB; ++q){
      int mid = (lo[q] + hi[q]) >> 1;
      uint T = (uint)(mid+1) << 19;
      u64 bal = __ballot(lmb[q] < T);
      bool c = __popcll(bal) >= 17;
      hi[q] = c ? mid : hi[q];
      lo[q] = c ? lo[q] : mid + 1;
    }
  }
  #pragma unroll
  for (int q = 0; q < QB; ++q){
    if (lane == 0) atomicMin(&sut[q], (uint)(lo[q]+2) << 19);  // +1 granule: fma-eps safety
  }
  __syncthreads();
  // cheap-collect thresholds (float domain, slack-inflated superset; r8/r9-proven)
  float Tc[QB];
  #pragma unroll
  for (int q = 0; q < QB; ++q){
    float Tf = __uint_as_float(sut[q]);
    float S  = (Qr[q].w + 16.0f) * 6.103515625e-05f;   // 2^-14
    Tc[q] = (Tf + S) - Qr[q].w;
  }
  // ---- stage B: full scan, CHEAP g-filter, store j only ----
  for (int s = 0; s < 16; ++s){
    int j = s*256 + tid;
    float4 p2 = posf[jbase + j];
    #pragma unroll
    for (int q = 0; q < QB; ++q){
      float g = __builtin_fmaf(Qr[q].x, p2.x, __builtin_fmaf(Qr[q].y, p2.y,
                __builtin_fmaf(Qr[q].z, p2.z, p2.w)));
      if (g < Tc[q]){
        int pc = atomicAdd(&scnt[q], 1);
        if (pc < CAP5) sjl[q][pc] = (ushort_t)j;
      }
    }
  }
  __syncthreads();
  // ---- stage C: rebuild EXACT keys per query, exact rank (wave-private) ----
  for (int q = wave; q < QB; q += 4){
    int cnt = scnt[q]; if (cnt > CAP5) cnt = CAP5;
    float4 Qq2 = posf[qbase + q];   // wave-uniform reload (avoids runtime-idx spill)
    float qx = -0.5f*Qq2.x, qy = -0.5f*Qq2.y, qz = -0.5f*Qq2.z, qw = Qq2.w;
    for (int base = 0; base < cnt; base += 64){
      int ci = base + lane;
      if (ci < cnt){
        int j = sjl[q][ci];
        float4 p2 = posf[jbase + j];
        float px = -0.5f*p2.x, py = -0.5f*p2.y, pz = -0.5f*p2.z;  // exact raw
        float ax = qx*px; float ay = qy*py; float az = qz*pz;
        float dot = (ax + ay) + az;               // match np einsum order
        float t  = qw + p2.w;
        float v  = t - 2.0f*dot;                  // bit-identical exact keys
        uint w = __float_as_uint(v);
        uint sd = w ^ ((w & 0x80000000u) ? 0xFFFFFFFFu : 0x80000000u); // signed monotone map
        kw[wave][ci] = (((u64)sd) << 32) | (uint)j;
      }
    }
    WAVE_SYNC();
    const u64* kwp = kw[wave];
    for (int base = 0; base < cnt; base += 64){
      int ci = base + lane;
      u64 mykey = (ci < cnt) ? kwp[ci] : ~0ull;
      int r = 0;
      int i = 0;
      #pragma unroll 2
      for (; i + 1 < cnt; i += 2){                // paired b128 broadcast reads
        u64x2 two = *(const u64x2*)&kwp[i];
        r += (two[0] < mykey) ? 1 : 0;
        r += (two[1] < mykey) ? 1 : 0;
      }
      if (i < cnt) r += (kwp[i] < mykey) ? 1 : 0;
      if (ci < cnt && r >= 1 && r <= 16)
        knn[(qbase + q)*16 + (r-1)] = (int)(mykey & 0xFFFFFFFFu);
    }
    WAVE_SYNC();   // keys of this query consumed before next query overwrites
  }
}

// ---------------- kernel W: weight prep ----------------
// Wtiles: 24 tiles x 1024 elems (2KB each), pre-swizzled SWZE image.
// tiles 0..3 = A1[nt]; 4..11 = B2[nt*2+kk]; 12..23 = C3[nt*3+kk].
__global__ __launch_bounds__(256) void k_wprep(const void* __restrict__ Wf, const void* __restrict__ bfv,
                        const void* __restrict__ Wm1, const void* __restrict__ bm1,
                        const void* __restrict__ Wm2, const void* __restrict__ bm2,
                        const void* __restrict__ Wl, const void* __restrict__ bl,
                        ushort_t* __restrict__ WcatT, float* __restrict__ biasT,
                        ushort_t* __restrict__ Wtiles,
                        const int* __restrict__ flag){
  int f32 = *flag;
  int id = blockIdx.x*256 + threadIdx.x;
  if (id < 40960){
    int n = id >> 7, k = id & 127;
    float v;
    if (n < 64)       v = ldin(Wf, (long)k*64 + n, f32) - ldin(Wf, (long)(256+k)*64 + n, f32);
    else if (n < 128) v = ldin(Wf, (long)(128+k)*64 + (n-64), f32) + ldin(Wf, (long)(256+k)*64 + (n-64), f32);
    else if (n < 192) v = ldin(Wm1, (long)(64+k)*64 + (n-128), f32);
    else if (n < 256) v = ldin(Wm2, (long)(128+k)*64 + (n-192), f32);
    else              v = ldin(Wl, (long)(192+k)*64 + (n-256), f32);
    WcatT[id] = f2bf(v);
  } else if (id < 41280){
    int n = id - 40960;
    float bv;
    if (n < 64)       bv = ldin(bfv, n, f32);
    else if (n < 128) bv = 0.0f;
    else if (n < 192) bv = ldin(bm1, n-128, f32);
    else if (n < 256) bv = ldin(bm2, n-192, f32);
    else              bv = ldin(bl, n-256, f32);
    biasT[n] = bv;
  } else if (id < 65856){      // Wtiles: 24576 elems
    int t2 = id - 41280;
    int tile = t2 >> 10;
    int r    = (t2 >> 6) & 15;
    int ep   = t2 & 63;
    int kl   = ep ^ ((r & 7) << 3);
    float v;
    if (tile < 4){
      int n = tile*16 + r;
      v = ldin(Wm1, (long)kl*64 + n, f32);
    } else if (tile < 12){
      int u = tile - 4; int n = (u >> 1)*16 + r; int k = (u & 1)*64 + kl;
      v = ldin(Wm2, (long)k*64 + n, f32);
    } else {
      int u = tile - 12; int n = (u / 3)*16 + r; int k = (u % 3)*64 + kl;
      v = ldin(Wl, (long)k*64 + n, f32);
    }
    Wtiles[t2] = f2bf(v);
  }
}

// ---------------- kernel 2: P = X @ Wcat + bias  (bf16 out, rows 32768 x 320) ----------------
__global__ __launch_bounds__(256) void k_pgemm(const void* __restrict__ xv, const ushort_t* __restrict__ WcatT,
                                               const float* __restrict__ biasT, ushort_t* __restrict__ P,
                                               const int* __restrict__ flag){
  int f32 = *flag;
  int wave = threadIdx.x >> 6, lane = threadIdx.x & 63;
  int rowbase = blockIdx.x*64 + wave*16;
  int quad = lane >> 4, col = lane & 15;
  floatx4 acc[20];
  #pragma unroll
  for (int i = 0; i < 20; ++i) acc[i] = (floatx4){0.f,0.f,0.f,0.f};
  #pragma unroll
  for (int kk = 0; kk < 4; ++kk){
    int k = kk*32 + quad*8;
    short8 a;
    if (f32){
      const float* xf = (const float*)xv + (long)(rowbase + col)*128 + k;
      #pragma unroll
      for (int i = 0; i < 8; ++i) a[i] = (short)f2bf(xf[i]);
    } else {
      a = *(const short8*)((const ushort_t*)xv + (long)(rowbase + col)*128 + k);
    }
    #pragma unroll
    for (int nt = 0; nt < 20; ++nt){
      short8 bb = *(const short8*)(WcatT + (nt*16 + col)*128 + k);
      acc[nt] = __builtin_amdgcn_mfma_f32_16x16x32_bf16(a, bb, acc[nt], 0, 0, 0);
    }
  }
  #pragma unroll
  for (int nt = 0; nt < 20; ++nt){
    float bv = biasT[nt*16 + col];
    #pragma unroll
    for (int r = 0; r < 4; ++r){
      int m = quad*4 + r;
      P[(long)(rowbase + m)*320 + nt*16 + col] = f2bf(acc[nt][r] + bv);
    }
  }
}

// ---------------- kernel 3: per-edge chain + max over K ----------------
// r7/r9-proven version VERBATIM. 512-thread blocks (8 waves), 512 blocks ->
// 2 blocks/CU, one clean round; idx preload + k/q gather prefetch only;
// u-values at iteration top; x in epilogue. C3 from global/L1.
__global__ __launch_bounds__(512) void k_edge(const void* __restrict__ x, const ushort_t* __restrict__ P,
                                              const int* __restrict__ knn,
                                              const ushort_t* __restrict__ Wg, void* __restrict__ out,
                                              const int* __restrict__ flag){
  __shared__ __align__(16) ushort_t wlds[12*1024];     // 24KB: A1 + B2
  __shared__ __align__(16) ushort_t hb[8][3][1024];    // 48KB: h1,h2,h3 per wave
  int f32 = *flag;
  int tid = threadIdx.x;
  int wave = tid >> 6, lane = tid & 63;
  int quad = lane >> 4, col = lane & 15;
  int qid0 = blockIdx.x*(8*NQE) + wave*NQE;
  int b = qid0 >> 12;                        // all NQE queries in same batch (64 | 4096)
  const ushort_t* Pb = P + ((long)(b<<12))*320;
  int e4 = lane >> 2, cg = lane & 3;

  // preload all neighbor indices (independent of LDS staging — issue first)
  int idxv[NQE];
  #pragma unroll
  for (int iq = 0; iq < NQE; ++iq)
    idxv[iq] = knn[(qid0+iq)*16 + e4] & (NP - 1);   // mask: corrupt idx stays in-bounds
  // prologue gather for query 0 (overlaps the staging barrier)
  short8 nk0 = *(const short8*)(Pb + (long)idxv[0]*320 + 64 + cg*16);
  short8 nk1 = *(const short8*)(Pb + (long)idxv[0]*320 + 64 + cg*16 + 8);
  short8 nq0 = *(const short8*)(P + (long)qid0*320 + cg*16);
  short8 nq1 = *(const short8*)(P + (long)qid0*320 + cg*16 + 8);

  // stage A1+B2: linear copy of the pre-swizzled image (conflict-free b128)
  #pragma unroll
  for (int i = 0; i < 3; ++i){
    int e = (i*512 + tid) << 3;
    *(short8*)(wlds + e) = *(const short8*)(Wg + e);
  }
  __syncthreads();
  const ushort_t* wA  = wlds;                // + nt*1024
  const ushort_t* wB  = wlds + 4*1024;       // + (nt*2+kk)*1024
  const ushort_t* wCg = Wg + 12*1024;        // + (nt*3+kk)*1024 (global, L1-hot)
  ushort_t* h1p = hb[wave][0];
  ushort_t* h2p = hb[wave][1];
  ushort_t* h3p = hb[wave][2];

  #pragma unroll
  for (int iq = 0; iq < NQE; ++iq){
    int qid = qid0 + iq;
    const ushort_t* Prow = P + (long)qid*320;
    long outb = (long)qid*384;

    float u1v[4], u2v[4], u3v[4];
    #pragma unroll
    for (int nt = 0; nt < 4; ++nt){
      u1v[nt] = bf2f(Prow[128 + nt*16 + col]);
      u2v[nt] = bf2f(Prow[192 + nt*16 + col]);
      u3v[nt] = bf2f(Prow[256 + nt*16 + col]);
    }

    short8 k0 = nk0, k1 = nk1, q0 = nq0, q1 = nq1;
    // prefetch next query's gather + Q-row (independent of current compute)
    if (iq + 1 < NQE){
      nk0 = *(const short8*)(Pb + (long)idxv[iq+1]*320 + 64 + cg*16);
      nk1 = *(const short8*)(Pb + (long)idxv[iq+1]*320 + 64 + cg*16 + 8);
      nq0 = *(const short8*)(P + (long)(qid+1)*320 + cg*16);
      nq1 = *(const short8*)(P + (long)(qid+1)*320 + cg*16 + 8);
    }

    // h1 = relu(q_i + k_j): lane -> edge e=e4, col-group cg
    {
      short8 h0, h1r;
      #pragma unroll
      for (int i = 0; i < 8; ++i){
        float v = fmaxf(bf2f((ushort_t)q0[i]) + bf2f((ushort_t)k0[i]), 0.0f);
        h0[i] = (short)f2bf(v);
        float w = fmaxf(bf2f((ushort_t)q1[i]) + bf2f((ushort_t)k1[i]), 0.0f);
        h1r[i] = (short)f2bf(w);
      }
      *(short8*)(h1p + SWZE(e4, cg*16))     = h0;
      *(short8*)(h1p + SWZE(e4, cg*16 + 8)) = h1r;
    }
    WAVE_SYNC();

    // layer 2: h2 = relu(h1 @ A1 + u1)
    floatx4 acc2[4];
    #pragma unroll
    for (int nt = 0; nt < 4; ++nt) acc2[nt] = (floatx4){0.f,0.f,0.f,0.f};
    #pragma unroll
    for (int kk = 0; kk < 2; ++kk){
      int k = kk*32 + quad*8;
      short8 a = *(const short8*)(h1p + SWZE(col, k));
      #pragma unroll
      for (int nt = 0; nt < 4; ++nt){
        short8 bb = *(const short8*)(wA + nt*1024 + SWZE(col, k));
        acc2[nt] = __builtin_amdgcn_mfma_f32_16x16x32_bf16(a, bb, acc2[nt], 0, 0, 0);
      }
    }
    #pragma unroll
    for (int nt = 0; nt < 4; ++nt){
      float v0 = fmaxf(acc2[nt][0] + u1v[nt], 0.0f);
      float v1 = fmaxf(acc2[nt][1] + u1v[nt], 0.0f);
      float v2 = fmaxf(acc2[nt][2] + u1v[nt], 0.0f);
      float v3 = fmaxf(acc2[nt][3] + u1v[nt], 0.0f);
      h2p[SWZE(quad*4+0, nt*16+col)] = f2bf(v0);
      h2p[SWZE(quad*4+1, nt*16+col)] = f2bf(v1);
      h2p[SWZE(quad*4+2, nt*16+col)] = f2bf(v2);
      h2p[SWZE(quad*4+3, nt*16+col)] = f2bf(v3);
      // store-early max: f2bf monotone => f2bf(max)==max(f2bf)
      float m2 = fmaxf(fmaxf(v0, v1), fmaxf(v2, v3));
      m2 = fmaxf(m2, __shfl_xor(m2, 16, 64));
      m2 = fmaxf(m2, __shfl_xor(m2, 32, 64));
      if (lane < 16) stout(out, outb + 128 + nt*16 + lane, bf2f(f2bf(m2)), f32);
    }
    WAVE_SYNC();

    // layer 3: h3 = relu([h2|h1] @ B2 + u2)
    floatx4 acc3[4];
    #pragma unroll
    for (int nt = 0; nt < 4; ++nt) acc3[nt] = (floatx4){0.f,0.f,0.f,0.f};
    #pragma unroll
    for (int kk = 0; kk < 4; ++kk){
      int kg = kk*32 + quad*8;
      const ushort_t* src = (kk < 2) ? h2p : h1p;
      int kl = (kk < 2) ? kg : (kg - 64);
      short8 a = *(const short8*)(src + SWZE(col, kl));
      #pragma unroll
      for (int nt = 0; nt < 4; ++nt){
        short8 bb = *(const short8*)(wB + (nt*2 + (kg>>6))*1024 + SWZE(col, kg & 63));
        acc3[nt] = __builtin_amdgcn_mfma_f32_16x16x32_bf16(a, bb, acc3[nt], 0, 0, 0);
      }
    }
    #pragma unroll
    for (int nt = 0; nt < 4; ++nt){
      float v0 = fmaxf(acc3[nt][0] + u2v[nt], 0.0f);
      float v1 = fmaxf(acc3[nt][1] + u2v[nt], 0.0f);
      float v2 = fmaxf(acc3[nt][2] + u2v[nt], 0.0f);
      float v3 = fmaxf(acc3[nt][3] + u2v[nt], 0.0f);
      h3p[SWZE(quad*4+0, nt*16+col)] = f2bf(v0);
      h3p[SWZE(quad*4+1, nt*16+col)] = f2bf(v1);
      h3p[SWZE(quad*4+2, nt*16+col)] = f2bf(v2);
      h3p[SWZE(quad*4+3, nt*16+col)] = f2bf(v3);
      float m3 = fmaxf(fmaxf(v0, v1), fmaxf(v2, v3));
      m3 = fmaxf(m3, __shfl_xor(m3, 16, 64));
      m3 = fmaxf(m3, __shfl_xor(m3, 32, 64));
      if (lane < 16) stout(out, outb + 64 + nt*16 + lane, bf2f(f2bf(m3)), f32);
    }
    WAVE_SYNC();

    // layer 4: o = [h3|h2|h1] @ C3 + u3  (no relu; C3 from global/L1)
    floatx4 acc4[4];
    #pragma unroll
    for (int nt = 0; nt < 4; ++nt) acc4[nt] = (floatx4){0.f,0.f,0.f,0.f};
    #pragma unroll
    for (int kk = 0; kk < 6; ++kk){
      int kg = kk*32 + quad*8;
      const ushort_t* src = (kk < 2) ? h3p : ((kk < 4) ? h2p : h1p);
      int kl = (kk < 2) ? kg : ((kk < 4) ? (kg - 64) : (kg - 128));
      short8 a = *(const short8*)(src + SWZE(col, kl));
      #pragma unroll
      for (int nt = 0; nt < 4; ++nt){
        short8 bb = *(const short8*)(wCg + (nt*3 + (kg>>6))*1024 + SWZE(col, kg & 63));
        acc4[nt] = __builtin_amdgcn_mfma_f32_16x16x32_bf16(a, bb, acc4[nt], 0, 0, 0);
      }
    }
    #pragma unroll
    for (int nt = 0; nt < 4; ++nt){
      float m0 = fmaxf(fmaxf(acc4[nt][0], acc4[nt][1]), fmaxf(acc4[nt][2], acc4[nt][3])) + u3v[nt];
      m0 = fmaxf(m0, __shfl_xor(m0, 16, 64));
      m0 = fmaxf(m0, __shfl_xor(m0, 32, 64));
      if (lane < 16) stout(out, outb + nt*16 + lane, m0, f32);
    }
    {
      ushort_t mx1 = 0;
      #pragma unroll
      for (int m = 0; m < 16; ++m){
        ushort_t v1u = h1p[SWZE(m, lane)]; if (v1u > mx1) mx1 = v1u;
      }
      // post-relu bf16 >= 0: bit compare == float compare
      stout(out, outb + 192 + lane, bf2f(mx1), f32);
      stout(out, outb + 256 + lane,      ldin(x, (long)qid*128 + lane, f32), f32);
      stout(out, outb + 256 + 64 + lane, ldin(x, (long)qid*128 + 64 + lane, f32), f32);
    }
    WAVE_SYNC();   // order h-tile reads of this query before next query's writes
  }
}

extern "C" void kernel_launch(void* const* d_in, const int* in_sizes, int n_in,
                              void* d_out, int out_size, void* d_ws, size_t ws_size,
                              hipStream_t stream){
  const void* x   = d_in[0];
  const void* pos = d_in[1];
  const void* Wf  = d_in[2];
  const void* bfv = d_in[3];
  const void* Wm1 = d_in[4];
  const void* bm1 = d_in[5];
  const void* Wm2 = d_in[6];
  const void* bm2 = d_in[7];
  const void* Wl  = d_in[8];
  const void* bl  = d_in[9];
  char* ws = (char*)d_ws;
  float4*   posf   = (float4*)(ws + 0);                 // 524288 B
  int*      knn    = (int*)(ws + 524288);               // 2097152 B
  ushort_t* P      = (ushort_t*)(ws + 2621440);         // 20971520 B
  ushort_t* WcatT  = (ushort_t*)(ws + 23592960);        // 81920 B
  float*    biasT  = (float*)(ws + 23674880);           // 1280 B
  ushort_t* Wtiles = (ushort_t*)(ws + 23676160);        // 49152 B (pre-swizzled SWZE image)
  int*      flag   = (int*)(ws + 23725312);             // 4 B (total ~22.63 MB)

  k_detect<<<1,    256, 0, stream>>>((const uint*)Wf, flag);
  k_posf <<<128,   256, 0, stream>>>(pos, posf, flag);
  k_wprep<<<258,   256, 0, stream>>>(Wf, bfv, Wm1, bm1, Wm2, bm2, Wl, bl, WcatT, biasT, Wtiles, flag);
  k_knn  <<<4096,  256, 0, stream>>>(posf, knn);
  k_pgemm<<<512,   256, 0, stream>>>(x, WcatT, biasT, P, flag);
  k_edge <<<512,   512, 0, stream>>>(x, P, knn, Wtiles, d_out, flag);
}